// Round 13
// baseline (254.483 us; speedup 1.0000x reference)
//
#include <hip/hip_runtime.h>
#include <stdint.h>

// Problem constants (fixed instance)
#define B_    32
#define S_    4096
#define E_    256
#define P_    256
#define M_    16
#define G_    (B_*P_)      // 8192 groups
#define NSLOT (G_*M_)      // 131072 slots (== tokens)
#define GPW   4            // groups per workgroup
#define ROWS  64           // 4 groups * 16 slots
#define NWG   (G_/GPW)     // 2048 workgroups

typedef float fv4 __attribute__((ext_vector_type(4)));
typedef int   iv4 __attribute__((ext_vector_type(4)));
typedef int   iv2 __attribute__((ext_vector_type(2)));
typedef __bf16 bv8 __attribute__((ext_vector_type(8)));
typedef short  sv4 __attribute__((ext_vector_type(4)));

__device__ __forceinline__ uint32_t bf16rne(float f) {
  uint32_t u = __builtin_bit_cast(uint32_t, f);
  u += 0x7fffu + ((u >> 16) & 1u);
  return u >> 16;
}
__device__ __forceinline__ uint32_t pk2(uint32_t lo, uint32_t hi) {
  return (lo & 0xffffu) | (hi << 16);
}
// Builtins (NOT inline asm): hazard recognizer must see MFMAs (round-1 NaN).
__device__ __forceinline__ void mfma32(fv4& d, iv4 a, iv4 b) {
  d = __builtin_amdgcn_mfma_f32_16x16x32_bf16(
        __builtin_bit_cast(bv8, a), __builtin_bit_cast(bv8, b), d, 0, 0, 0);
}
__device__ __forceinline__ void mfma16(fv4& d, iv2 a, iv2 b) {
  d = __builtin_amdgcn_mfma_f32_16x16x16bf16_1k(
        __builtin_bit_cast(sv4, a), __builtin_bit_cast(sv4, b), d, 0, 0, 0);
}
// async global->LDS, 16B/lane; LDS dest = wave-uniform base + lane*16.
__device__ __forceinline__ void gload_lds16(const void* g, void* l) {
  __builtin_amdgcn_global_load_lds(
      (const __attribute__((address_space(1))) uint32_t*)g,
      (__attribute__((address_space(3))) uint32_t*)l, 16, 0, 0);
}

// XOR swizzle for 512B rows: flips byte bits 4-6 by row&7 (involution).
#define SWZ(off, row) ((off) ^ (((row) & 7) << 4))
// 64B-row buffers (Q/K/V/C [64][32]bf16) stored [pair][128B], pair-swizzled.
#define LQKV(row, cb) ( ((row) >> 1) * 128 + \
    (((((row) & 1) << 6) + (cb)) ^ ((((row) >> 1) & 7) << 4)) )

// Raw barrier + counted waits (T3/T4): loads stay in flight across barriers.
// VALID ONLY IF THE LOOP BODY IS SPILL-FREE: scratch ops count in vmcnt and
// corrupt the ledger. r11 ((512,4)+xf cache) and r12 ((512,4)+Xb) both
// failed: the (512,4) pin is a ~64-reg TOTAL (arch+AGPR) budget, and
// demand ~77 spilled in-loop. (512,2) = 128 budget; r6 proved the identical
// slot/ledger structure correct there with WRITE==output exactly.
#define BAR()   { asm volatile("" ::: "memory"); __builtin_amdgcn_s_barrier(); \
                  asm volatile("" ::: "memory"); }
#define VMWAIT2 asm volatile("s_waitcnt vmcnt(2)" ::: "memory")
#define VMWAIT0 asm volatile("s_waitcnt vmcnt(0)" ::: "memory")
#define LGKM0   asm volatile("s_waitcnt lgkmcnt(0)" ::: "memory")

// ---------------- prep kernels ----------------
__global__ void k_init(int* cnt, int* s2t) {
  int i = blockIdx.x * 256 + threadIdx.x;
  if (i < G_) cnt[i] = 0;
  if (i < NSLOT) s2t[i] = -1;
}

__global__ void k_trans(const float* __restrict__ Wq, const float* __restrict__ Wk,
                        const float* __restrict__ Wv, const float* __restrict__ W0,
                        uint16_t* __restrict__ WT) {
  // WT: 4 concatenated [256][256] bf16, WT[w][n][k] = bf16(W[w][k][n])
  int o = blockIdx.x * 256 + threadIdx.x;     // 0..65535
  int wsel = blockIdx.y;
  const float* W = (wsel == 0) ? Wq : (wsel == 1) ? Wk : (wsel == 2) ? Wv : W0;
  int n = o >> 8, k = o & 255;
  WT[(size_t)wsel * 65536 + o] = (uint16_t)bf16rne(W[k * 256 + n]);
}

__global__ void k_rank(const int* __restrict__ pos, int* cnt, int* s2t) {
  int i = blockIdx.x * 256 + threadIdx.x;
  if (i >= B_ * S_) return;
  int p = pos[i];
  if (p < 0 || p >= P_) return;          // invalid -> dropped (stays -1)
  int b = i >> 12;                       // i / S_
  int g = (b << 8) + p;
  int r = atomicAdd(&cnt[g], 1);         // arbitrary slot order: attention is
  if (r < M_) s2t[g * M_ + r] = i;       // permutation-equivariant, so OK
}

// stage one QKV weight tile (16 KiB = 32 n-rows x 512B): 2 instrs/wave.
__device__ __forceinline__ void stage_qkv(const uint16_t* Wt, int c0, char* buf,
                                          int w, int l) {
  #pragma unroll
  for (int it = 0; it < 2; ++it) {
    int q = it * 8 + w;                  // 0..15, 1 KiB per instr
    int n = q * 2 + (l >> 5);            // local n-row 0..31
    int seg = l & 31;
    gload_lds16(reinterpret_cast<const char*>(Wt) + (size_t)(c0 + n) * 512 + SWZ(seg * 16, n),
                buf + q * 1024);
  }
}
// stage W0 k-slice tile (16 KiB): [256 n][64B] as [128 pair][128B], swizzled.
__device__ __forceinline__ void stage_w0(const uint16_t* W0T, int c0, char* buf,
                                         int w, int l) {
  #pragma unroll
  for (int it = 0; it < 2; ++it) {
    int q = it * 8 + w;
    int pair = q * 8 + (l >> 3);         // 0..127
    int jp = ((l & 7) * 16) ^ ((pair & 7) << 4);
    int n = 2 * pair + (jp >> 6);
    gload_lds16(reinterpret_cast<const char*>(W0T) + (size_t)n * 512 + c0 * 2 + (jp & 63),
                buf + q * 1024);
  }
}

// ---------------- fused main kernel ----------------
// 1 WG = 4 groups = 64 rows, 512 threads = 8 waves; LDS 80 KiB -> exactly
// 2 WGs/CU (160 KiB). Two INDEPENDENT barrier groups per CU: one WG's
// barrier/vmcnt drain overlaps the other's MFMA phases.
// Spill-free by construction: X stays in LDS (no xf[8] register cache);
// arch demand ~50 + 32 AGPR = ~82 total, well under (512,2)'s 128 budget
// -> no scratch ops -> counted-vmcnt ledger exact (r11/r12 lesson: the
// (512,4) 64-reg pin forced in-loop spills that corrupted vmcnt counts).
// Slot stream Wq,Wk,Wv,W0 per 32-col chunk, 2-deep ping-pong
// (2 instrs/wave/tile): at consumer slot own outstanding = 4 (tiles t,t+1);
// VMWAIT2 completes t; VMWAIT0 @ hc=7.
__global__ __launch_bounds__(512, 2) void k_main(
    const float* __restrict__ emb, const int* __restrict__ s2t,
    const uint16_t* __restrict__ WT, float* __restrict__ out) {
  extern __shared__ char smem[];
  char* Xb   = smem;            // 32 KiB [64][512B] bf16 X, row-swizzled
  char* bufA = smem + 32768;    // 16 KiB
  char* bufB = smem + 49152;    // 16 KiB
  char* Qb = smem + 65536;      // 4 KiB [64][32] bf16, pair-swizzled
  char* Kb = smem + 69632;
  char* Vb = smem + 73728;
  char* Cb = smem + 77824;      // total 80 KiB

  const uint16_t* WqT = WT;
  const uint16_t* WkT = WT + 65536;
  const uint16_t* WvT = WT + 131072;
  const uint16_t* W0T = WT + 196608;

  const int tid = threadIdx.x;
  const int l = tid & 63;
  const int w = tid >> 6;           // wave 0..7
  const int lane15 = l & 15;
  const int lq = l >> 4;            // lane quad 0..3
  const int rb = w >> 1;            // 16-row block 0..3
  const int ch = w & 1;             // col half
  const int slot0 = blockIdx.x * ROWS;

  // ---- gather: 64 token rows -> bf16 X in Xb (coalesced 1KB row loads) ----
  #pragma unroll 2
  for (int rl = 0; rl < 8; ++rl) {
    int row = w * 8 + rl;
    int t = s2t[slot0 + row];            // wave-uniform (scalar load)
    uint32_t u0 = 0, u1 = 0;
    if (t >= 0) {
      const float4 v = *reinterpret_cast<const float4*>(emb + (size_t)t * E_ + (l << 2));
      u0 = pk2(bf16rne(v.x), bf16rne(v.y));
      u1 = pk2(bf16rne(v.z), bf16rne(v.w));
    }
    iv2 val; val[0] = (int)u0; val[1] = (int)u1;
    *reinterpret_cast<iv2*>(Xb + row * 512 + SWZ(l * 8, row)) = val;
  }
  __syncthreads();   // X resident for the whole kernel (all gather vmem drained)

  fv4 outacc[8];     // 16 rows x 128 cols per wave (AGPR), persists
  #pragma unroll
  for (int i = 0; i < 8; ++i) outacc[i] = fv4{0.f, 0.f, 0.f, 0.f};

  // prologue: 2 tiles in flight (4 vmem instrs/wave)
  stage_qkv(WqT, 0, bufA, w, l);
  stage_qkv(WkT, 0, bufB, w, l);

  for (int hc = 0; hc < 8; ++hc) {       // 8 chunks of 32 cols (1 head)
    const int c0 = hc * 32;

    // QKV projection: wave computes 16 rows x 16 cols (8 MFMA); A-fragments
    // re-read from Xb each ks (keeps register demand low -> no spills)
    #define COMPUTE_QKV(buf, dst)                                            \
    {                                                                        \
      fv4 a0 = fv4{0.f,0.f,0.f,0.f};                                         \
      const int n0 = ch * 16 + lane15;                                       \
      const int ar2 = rb * 16 + lane15;                                      \
      _Pragma("unroll")                                                      \
      for (int ks = 0; ks < 8; ++ks) {                                       \
        iv4 av = *reinterpret_cast<const iv4*>(Xb + ar2 * 512 + SWZ(ks * 64 + lq * 16, ar2)); \
        iv4 b0 = *reinterpret_cast<const iv4*>((buf) + n0 * 512 + SWZ(ks * 64 + lq * 16, n0)); \
        mfma32(a0, av, b0);                                                  \
      }                                                                      \
      _Pragma("unroll")                                                      \
      for (int r = 0; r < 4; ++r) {                                          \
        int row = rb * 16 + lq * 4 + r;                                      \
        *reinterpret_cast<uint16_t*>((dst) + LQKV(row, n0 * 2)) =            \
            (uint16_t)bf16rne(a0[r]);                                        \
      }                                                                      \
    }

    // slot 0: Wq tile in bufA
    VMWAIT2; BAR();
    COMPUTE_QKV(bufA, Qb);
    LGKM0; BAR();
    stage_qkv(WvT, c0, bufA, w, l);      // issue Wv(hc)

    // slot 1: Wk tile in bufB
    VMWAIT2; BAR();
    COMPUTE_QKV(bufB, Kb);
    LGKM0; BAR();
    stage_w0(W0T, c0, bufB, w, l);       // issue W0(hc)

    // slot 2: Wv tile in bufA
    VMWAIT2; BAR();
    COMPUTE_QKV(bufA, Vb);
    LGKM0; BAR();
    if (hc < 7) stage_qkv(WqT, c0 + 32, bufA, w, l);   // issue Wq(hc+1)

    // ---- attention: pair g = rb, head = hc; V-half split by ch ----
    {
      const int frow = rb * 16 + lane15;
      iv4 kf = *reinterpret_cast<const iv4*>(Kb + LQKV(frow, lq * 16));
      iv4 qf = *reinterpret_cast<const iv4*>(Qb + LQKV(frow, lq * 16));
      fv4 s = fv4{0.f, 0.f, 0.f, 0.f};
      mfma32(s, kf, qf);                 // swapped QK^T (pair-dup by ch, cheap)
      float mx = fmaxf(fmaxf(s[0], s[1]), fmaxf(s[2], s[3]));
      mx = fmaxf(mx, __shfl_xor(mx, 16));
      mx = fmaxf(mx, __shfl_xor(mx, 32));
      const float Cc = 0.25503373f;      // log2(e)/sqrt(32)
      float e0 = exp2f((s[0] - mx) * Cc), e1 = exp2f((s[1] - mx) * Cc);
      float e2 = exp2f((s[2] - mx) * Cc), e3 = exp2f((s[3] - mx) * Cc);
      float sum = e0 + e1 + e2 + e3;
      sum += __shfl_xor(sum, 16);
      sum += __shfl_xor(sum, 32);
      float inv = 1.0f / sum;
      iv2 pa; pa[0] = (int)pk2(bf16rne(e0 * inv), bf16rne(e1 * inv));
              pa[1] = (int)pk2(bf16rne(e2 * inv), bf16rne(e3 * inv));
      const int r0 = rb * 16 + lq * 4;
      const int cb = (ch * 16 + lane15) * 2;
      uint32_t v0 = *reinterpret_cast<const uint16_t*>(Vb + LQKV(r0 + 0, cb));
      uint32_t v1 = *reinterpret_cast<const uint16_t*>(Vb + LQKV(r0 + 1, cb));
      uint32_t v2 = *reinterpret_cast<const uint16_t*>(Vb + LQKV(r0 + 2, cb));
      uint32_t v3 = *reinterpret_cast<const uint16_t*>(Vb + LQKV(r0 + 3, cb));
      iv2 bv; bv[0] = (int)pk2(v0, v1); bv[1] = (int)pk2(v2, v3);
      fv4 cacc = fv4{0.f, 0.f, 0.f, 0.f};
      mfma16(cacc, pa, bv);
      #pragma unroll
      for (int r = 0; r < 4; ++r)
        *reinterpret_cast<uint16_t*>(Cb + LQKV(r0 + r, cb)) =
            (uint16_t)bf16rne(cacc[r]);
    }

    // slot 3: W0 tile in bufB (LGKM0 also publishes attn's Cb writes)
    if (hc < 7) { VMWAIT2; } else { VMWAIT0; }
    LGKM0; BAR();
    {
      int ar = rb * 16 + lane15;
      iv4 af = *reinterpret_cast<const iv4*>(Cb + LQKV(ar, lq * 16));
      #pragma unroll
      for (int nt = 0; nt < 8; ++nt) {
        int n = ch * 128 + nt * 16 + lane15;
        iv4 bfg = *reinterpret_cast<const iv4*>(
            bufB + (n >> 1) * 128 + ((((n & 1) << 6) + lq * 16) ^ (((n >> 1) & 7) << 4)));
        mfma32(outacc[nt], af, bfg);
      }
    }
    BAR();
    if (hc < 7) stage_qkv(WkT, c0 + 32, bufB, w, l);   // issue Wk(hc+1)
    #undef COMPUTE_QKV
  } // hc

  // ---- scatter out (fp32, 64B segments per 16-lane group) ----
  #pragma unroll
  for (int r = 0; r < 4; ++r) {
    int t = s2t[slot0 + rb * 16 + lq * 4 + r];
    if (t < 0) continue;
    #pragma unroll
    for (int nt = 0; nt < 8; ++nt) {
      int col = ch * 128 + nt * 16 + lane15;
      out[(size_t)t * E_ + col] = outacc[nt][r];
    }
  }
}

extern "C" void kernel_launch(void* const* d_in, const int* in_sizes, int n_in,
                              void* d_out, int out_size, void* d_ws, size_t ws_size,
                              hipStream_t stream) {
  (void)in_sizes; (void)n_in; (void)out_size; (void)ws_size;
  const float* emb = (const float*)d_in[0];
  const float* Wq  = (const float*)d_in[1];
  const float* Wk  = (const float*)d_in[2];
  const float* Wv  = (const float*)d_in[3];
  const float* W0  = (const float*)d_in[4];
  const int*   pos = (const int*)d_in[5];
  float* out = (float*)d_out;

  // ws layout: cnt 32KB | s2t 512KB | WT(4x bf16 256x256) 512KB
  int* cnt = (int*)d_ws;
  int* s2t = (int*)((char*)d_ws + 32768);
  uint16_t* WT = (uint16_t*)((char*)d_ws + 32768 + 524288);

  (void)hipFuncSetAttribute(reinterpret_cast<const void*>(k_main),
                            hipFuncAttributeMaxDynamicSharedMemorySize, 81920);

  k_init <<<512, 256, 0, stream>>>(cnt, s2t);
  k_trans<<<dim3(256, 4), 256, 0, stream>>>(Wq, Wk, Wv, W0, WT);
  k_rank <<<512, 256, 0, stream>>>(pos, cnt, s2t);
  k_main <<<NWG, 512, 81920, stream>>>(emb, s2t, WT, out);
}

// Round 14
// 231.220 us; speedup vs baseline: 1.1006x; 1.1006x over previous
//
#include <hip/hip_runtime.h>
#include <stdint.h>

// Problem constants (fixed instance)
#define B_    32
#define S_    4096
#define E_    256
#define P_    256
#define M_    16
#define G_    (B_*P_)      // 8192 groups
#define NSLOT (G_*M_)      // 131072 slots (== tokens)
#define GPW   8            // groups per workgroup
#define ROWS  128          // 8 groups * 16 slots
#define NWG   (G_/GPW)     // 1024 workgroups

typedef float fv4 __attribute__((ext_vector_type(4)));
typedef int   iv4 __attribute__((ext_vector_type(4)));
typedef int   iv2 __attribute__((ext_vector_type(2)));
typedef __bf16 bv8 __attribute__((ext_vector_type(8)));
typedef short  sv4 __attribute__((ext_vector_type(4)));

__device__ __forceinline__ uint32_t bf16rne(float f) {
  uint32_t u = __builtin_bit_cast(uint32_t, f);
  u += 0x7fffu + ((u >> 16) & 1u);
  return u >> 16;
}
__device__ __forceinline__ uint32_t pk2(uint32_t lo, uint32_t hi) {
  return (lo & 0xffffu) | (hi << 16);
}
// Builtins (NOT inline asm): hazard recognizer must see MFMAs (round-1 NaN).
__device__ __forceinline__ void mfma32(fv4& d, iv4 a, iv4 b) {
  d = __builtin_amdgcn_mfma_f32_16x16x32_bf16(
        __builtin_bit_cast(bv8, a), __builtin_bit_cast(bv8, b), d, 0, 0, 0);
}
__device__ __forceinline__ void mfma16(fv4& d, iv2 a, iv2 b) {
  d = __builtin_amdgcn_mfma_f32_16x16x16bf16_1k(
        __builtin_bit_cast(sv4, a), __builtin_bit_cast(sv4, b), d, 0, 0, 0);
}
// async global->LDS, 16B/lane; LDS dest = wave-uniform base + lane*16.
__device__ __forceinline__ void gload_lds16(const void* g, void* l) {
  __builtin_amdgcn_global_load_lds(
      (const __attribute__((address_space(1))) uint32_t*)g,
      (__attribute__((address_space(3))) uint32_t*)l, 16, 0, 0);
}

// XOR swizzle for 512B rows: flips byte bits 4-6 by row&7 (involution).
#define SWZ(off, row) ((off) ^ (((row) & 7) << 4))
// 64B-row buffers (Q/K/V/C [128][32]bf16) stored [pair][128B], pair-swizzled.
#define LQKV(row, cb) ( ((row) >> 1) * 128 + \
    (((((row) & 1) << 6) + (cb)) ^ ((((row) >> 1) & 7) << 4)) )

// Raw barrier + counted waits (T3/T4). Ledger valid because the loop body is
// spill-free (r11/r12 lesson: scratch ops count in vmcnt; r8's loop was
// clean — spills confined to prologue/epilogue — and this keeps its shape).
#define BAR()   { asm volatile("" ::: "memory"); __builtin_amdgcn_s_barrier(); \
                  asm volatile("" ::: "memory"); }
#define VMWAIT2 asm volatile("s_waitcnt vmcnt(2)" ::: "memory")
#define VMWAIT0 asm volatile("s_waitcnt vmcnt(0)" ::: "memory")
#define LGKM0   asm volatile("s_waitcnt lgkmcnt(0)" ::: "memory")

// ---------------- prep kernels ----------------
__global__ void k_init(int* cnt, int* s2t) {
  int i = blockIdx.x * 256 + threadIdx.x;
  if (i < G_) cnt[i] = 0;
  if (i < NSLOT) s2t[i] = -1;
}

__global__ void k_trans(const float* __restrict__ Wq, const float* __restrict__ Wk,
                        const float* __restrict__ Wv, const float* __restrict__ W0,
                        uint16_t* __restrict__ WT) {
  // WT: 4 concatenated [256][256] bf16, WT[w][n][k] = bf16(W[w][k][n])
  int o = blockIdx.x * 256 + threadIdx.x;     // 0..65535
  int wsel = blockIdx.y;
  const float* W = (wsel == 0) ? Wq : (wsel == 1) ? Wk : (wsel == 2) ? Wv : W0;
  int n = o >> 8, k = o & 255;
  WT[(size_t)wsel * 65536 + o] = (uint16_t)bf16rne(W[k * 256 + n]);
}

__global__ void k_rank(const int* __restrict__ pos, int* cnt, int* s2t) {
  int i = blockIdx.x * 256 + threadIdx.x;
  if (i >= B_ * S_) return;
  int p = pos[i];
  if (p < 0 || p >= P_) return;          // invalid -> dropped (stays -1)
  int b = i >> 12;                       // i / S_
  int g = (b << 8) + p;
  int r = atomicAdd(&cnt[g], 1);         // arbitrary slot order: attention is
  if (r < M_) s2t[g * M_ + r] = i;       // permutation-equivariant, so OK
}

// stage one QKV weight tile (16 KiB): 1 gload instr per wave (1 KiB).
__device__ __forceinline__ void stage_qkv(const uint16_t* Wt, int c0, char* buf,
                                          int w, int l) {
  int n = w * 2 + (l >> 5);              // local n-row 0..31
  int seg = l & 31;
  gload_lds16(reinterpret_cast<const char*>(Wt) + (size_t)(c0 + n) * 512 + SWZ(seg * 16, n),
              buf + w * 1024);
}
// stage W0 k-slice tile: [256 n][64B], stored [128 pair][128B] pair-swizzled.
__device__ __forceinline__ void stage_w0(const uint16_t* W0T, int c0, char* buf,
                                         int w, int l) {
  int pair = w * 8 + (l >> 3);           // 0..127
  int jp = ((l & 7) * 16) ^ ((pair & 7) << 4);
  int n = 2 * pair + (jp >> 6);
  gload_lds16(reinterpret_cast<const char*>(W0T) + (size_t)n * 512 + c0 * 2 + (jp & 63),
              buf + w * 1024);
}

// ---------------- fused main kernel ----------------
// 1 WG = 8 groups = 128 rows, 1024 threads = 16 waves. Occupancy model
// (fits r2..r13): waves/SIMD = floor(256/archVGPR); 1024-thr WGs get
// arch pinned to 64 -> 4 waves/SIMD = 16 waves/CU (1 WG).
// r14 change vs r8: THREE rotating 16 KiB stage buffers (tile t -> buf t%3),
// ONE barrier per slot (entry VMWAIT2+BAR; stage for tile t+2 issued right
// after — 2 slots of latency cover vs r8's 1), 5 barriers/chunk vs 8.
// Tile stream: t = 4*hc + {0:Wq,1:Wk,2:Wv,3:W0}. Ledger (2 instrs/tile,
// 1024 threads -> stage_qkv/w0 = 1 instr? NO: 16 waves -> 1 instr/wave
// covers 16 KiB; 2 tiles outstanding = 2 instrs... see below): with 16
// waves each stage fn issues exactly 1 vmem instr/wave, so outstanding at
// slot entry = 2 (tiles t, t+1) -> VMWAIT2 would be wrong; it's vmcnt
// counts INSTRUCTIONS: 2 outstanding -> wait vmcnt(1) completes tile t.
// CORRECTED LEDGER: 1 instr/wave/tile -> at slot entry own outstanding = 2
// (t, t+1) -> VMWAIT1 completes t; VMWAIT0 at the last tile.
#undef VMWAIT2
#define VMWAIT1 asm volatile("s_waitcnt vmcnt(1)" ::: "memory")
__global__ __launch_bounds__(1024) void k_main(
    const float* __restrict__ emb, const int* __restrict__ s2t,
    const uint16_t* __restrict__ WT, float* __restrict__ out) {
  extern __shared__ char smem[];
  // 3 x 16 KiB rotating stage buffers
  char* Qb = smem + 49152;      // 8 KiB [128][32] bf16, pair-swizzled
  char* Kb = smem + 57344;
  char* Vb = smem + 65536;
  char* Cb = smem + 73728;      // total 80 KiB

  const int tid = threadIdx.x;
  const int l = tid & 63;
  const int w = tid >> 6;           // wave 0..15
  const int lane15 = l & 15;
  const int lq = l >> 4;            // lane quad 0..3
  const int rb = w >> 1;            // 16-row block 0..7
  const int ch = w & 1;             // col half
  const int slot0 = blockIdx.x * ROWS;

  // ---- gather: 128 token rows -> bf16 X overlay on smem[0..64K) ----
  #pragma unroll 2
  for (int rl = 0; rl < 8; ++rl) {
    int row = w * 8 + rl;
    int t = s2t[slot0 + row];            // wave-uniform (scalar load)
    uint32_t u0 = 0, u1 = 0;
    if (t >= 0) {
      const float4 v = *reinterpret_cast<const float4*>(emb + (size_t)t * E_ + (l << 2));
      u0 = pk2(bf16rne(v.x), bf16rne(v.y));
      u1 = pk2(bf16rne(v.z), bf16rne(v.w));
    }
    iv2 val; val[0] = (int)u0; val[1] = (int)u1;
    *reinterpret_cast<iv2*>(smem + row * 512 + SWZ(l * 8, row)) = val;
  }
  __syncthreads();

  // ---- X A-fragments: rows rb*16..+16, full K (32 VGPR) ----
  iv4 xf[8];
  const int arow = rb * 16 + lane15;
  #pragma unroll
  for (int ks = 0; ks < 8; ++ks)
    xf[ks] = *reinterpret_cast<const iv4*>(smem + arow * 512 + SWZ(ks * 64 + lq * 16, arow));
  __syncthreads();   // all xf read; overlay region now reusable

  fv4 outacc[8];     // 16 rows x 128 cols per wave (AGPR), persists
  #pragma unroll
  for (int i = 0; i < 8; ++i) outacc[i] = fv4{0.f, 0.f, 0.f, 0.f};

  const uint16_t* W0T = WT + 196608;

  // issue tile j (j<32): kind j&3 in {Wq,Wk,Wv,W0}, chunk j>>2, buf j%3.
  #define ISSUE(j)                                                           \
    if ((j) < 32) {                                                          \
      char* bj = smem + ((j) % 3) * 16384;                                   \
      int kind = (j) & 3, cc = ((j) >> 2) * 32;                              \
      if (kind == 3) stage_w0(W0T, cc, bj, w, l);                            \
      else stage_qkv(WT + kind * 65536, cc, bj, w, l);                       \
    }
  #define BUF(j) (smem + ((j) % 3) * 16384)

  // prologue: tiles 0 (Wq0) and 1 (Wk0) in flight
  ISSUE(0); ISSUE(1);

  for (int hc = 0; hc < 8; ++hc) {       // 8 chunks of 32 cols (1 head)
    const int t0 = hc * 4;

    // QKV projection: wave computes 16 rows x 16 cols (8 MFMA) from tile
    #define COMPUTE_QKV(buf, dst)                                            \
    {                                                                        \
      fv4 a0 = fv4{0.f,0.f,0.f,0.f};                                         \
      const int n0 = ch * 16 + lane15;                                       \
      _Pragma("unroll")                                                      \
      for (int ks = 0; ks < 8; ++ks) {                                       \
        iv4 b0 = *reinterpret_cast<const iv4*>((buf) + n0 * 512 + SWZ(ks * 64 + lq * 16, n0)); \
        mfma32(a0, xf[ks], b0);                                              \
      }                                                                      \
      _Pragma("unroll")                                                      \
      for (int r = 0; r < 4; ++r) {                                          \
        int row = rb * 16 + lq * 4 + r;                                      \
        *reinterpret_cast<uint16_t*>((dst) + LQKV(row, n0 * 2)) =            \
            (uint16_t)bf16rne(a0[r]);                                        \
      }                                                                      \
    }

    // slot 0: Wq(hc) in BUF(t0)
    VMWAIT1; BAR();
    ISSUE(t0 + 2);                       // Wv(hc), 2 slots ahead
    COMPUTE_QKV(BUF(t0), Qb);
    LGKM0;

    // slot 1: Wk(hc) in BUF(t0+1)
    VMWAIT1; BAR();
    ISSUE(t0 + 3);                       // W0(hc)
    COMPUTE_QKV(BUF(t0 + 1), Kb);
    LGKM0;

    // slot 2: Wv(hc) in BUF(t0+2)
    VMWAIT1; BAR();
    ISSUE(t0 + 4);                       // Wq(hc+1)
    COMPUTE_QKV(BUF(t0 + 2), Vb);
    LGKM0;

    // slot 3: W0(hc) in BUF(t0+3); attn first (Q/K/V visible via BAR)
    if (t0 + 3 == 31) { VMWAIT0; } else { VMWAIT1; }
    BAR();
    ISSUE(t0 + 5);                       // Wk(hc+1)
    {
      const int frow = rb * 16 + lane15;
      iv4 kf = *reinterpret_cast<const iv4*>(Kb + LQKV(frow, lq * 16));
      iv4 qf = *reinterpret_cast<const iv4*>(Qb + LQKV(frow, lq * 16));
      fv4 s = fv4{0.f, 0.f, 0.f, 0.f};
      mfma32(s, kf, qf);                 // swapped QK^T (pair-dup by ch, cheap)
      float mx = fmaxf(fmaxf(s[0], s[1]), fmaxf(s[2], s[3]));
      mx = fmaxf(mx, __shfl_xor(mx, 16));
      mx = fmaxf(mx, __shfl_xor(mx, 32));
      const float Cc = 0.25503373f;      // log2(e)/sqrt(32)
      float e0 = exp2f((s[0] - mx) * Cc), e1 = exp2f((s[1] - mx) * Cc);
      float e2 = exp2f((s[2] - mx) * Cc), e3 = exp2f((s[3] - mx) * Cc);
      float sum = e0 + e1 + e2 + e3;
      sum += __shfl_xor(sum, 16);
      sum += __shfl_xor(sum, 32);
      float inv = 1.0f / sum;
      iv2 pa; pa[0] = (int)pk2(bf16rne(e0 * inv), bf16rne(e1 * inv));
              pa[1] = (int)pk2(bf16rne(e2 * inv), bf16rne(e3 * inv));
      const int r0 = rb * 16 + lq * 4;
      const int cb = (ch * 16 + lane15) * 2;
      uint32_t v0 = *reinterpret_cast<const uint16_t*>(Vb + LQKV(r0 + 0, cb));
      uint32_t v1 = *reinterpret_cast<const uint16_t*>(Vb + LQKV(r0 + 1, cb));
      uint32_t v2 = *reinterpret_cast<const uint16_t*>(Vb + LQKV(r0 + 2, cb));
      uint32_t v3 = *reinterpret_cast<const uint16_t*>(Vb + LQKV(r0 + 3, cb));
      iv2 bv; bv[0] = (int)pk2(v0, v1); bv[1] = (int)pk2(v2, v3);
      fv4 cacc = fv4{0.f, 0.f, 0.f, 0.f};
      mfma16(cacc, pa, bv);
      #pragma unroll
      for (int r = 0; r < 4; ++r)
        *reinterpret_cast<uint16_t*>(Cb + LQKV(r0 + r, cb)) =
            (uint16_t)bf16rne(cacc[r]);
    }
    LGKM0; BAR();                        // Cb cross-wave visible

    // W0-accum: out += ctx_chunk @ W0[c0:c0+32, :]
    {
      int ar = rb * 16 + lane15;
      iv4 af = *reinterpret_cast<const iv4*>(Cb + LQKV(ar, lq * 16));
      char* wb = BUF(t0 + 3);
      #pragma unroll
      for (int nt = 0; nt < 8; ++nt) {
        int n = ch * 128 + nt * 16 + lane15;
        iv4 bfg = *reinterpret_cast<const iv4*>(
            wb + (n >> 1) * 128 + ((((n & 1) << 6) + lq * 16) ^ (((n >> 1) & 7) << 4)));
        mfma32(outacc[nt], af, bfg);
      }
    }
    LGKM0;
    #undef COMPUTE_QKV
  } // hc
  #undef ISSUE
  #undef BUF

  // ---- scatter out (fp32, 64B segments per 16-lane group) ----
  #pragma unroll
  for (int r = 0; r < 4; ++r) {
    int t = s2t[slot0 + rb * 16 + lq * 4 + r];
    if (t < 0) continue;
    #pragma unroll
    for (int nt = 0; nt < 8; ++nt) {
      int col = ch * 128 + nt * 16 + lane15;
      out[(size_t)t * E_ + col] = outacc[nt][r];
    }
  }
}

extern "C" void kernel_launch(void* const* d_in, const int* in_sizes, int n_in,
                              void* d_out, int out_size, void* d_ws, size_t ws_size,
                              hipStream_t stream) {
  (void)in_sizes; (void)n_in; (void)out_size; (void)ws_size;
  const float* emb = (const float*)d_in[0];
  const float* Wq  = (const float*)d_in[1];
  const float* Wk  = (const float*)d_in[2];
  const float* Wv  = (const float*)d_in[3];
  const float* W0  = (const float*)d_in[4];
  const int*   pos = (const int*)d_in[5];
  float* out = (float*)d_out;

  // ws layout: cnt 32KB | s2t 512KB | WT(4x bf16 256x256) 512KB
  int* cnt = (int*)d_ws;
  int* s2t = (int*)((char*)d_ws + 32768);
  uint16_t* WT = (uint16_t*)((char*)d_ws + 32768 + 524288);

  (void)hipFuncSetAttribute(reinterpret_cast<const void*>(k_main),
                            hipFuncAttributeMaxDynamicSharedMemorySize, 81920);

  k_init <<<512, 256, 0, stream>>>(cnt, s2t);
  k_trans<<<dim3(256, 4), 256, 0, stream>>>(Wq, Wk, Wv, W0, WT);
  k_rank <<<512, 256, 0, stream>>>(pos, cnt, s2t);
  k_main <<<NWG, 1024, 81920, stream>>>(emb, s2t, WT, out);
}